// Round 4
// baseline (160.158 us; speedup 1.0000x reference)
//
#include <hip/hip_runtime.h>
#include <hip/hip_bf16.h>

typedef short bf16x8 __attribute__((ext_vector_type(8)));
typedef float f32x4 __attribute__((ext_vector_type(4)));
typedef float f32x16 __attribute__((ext_vector_type(16)));
typedef unsigned short u16;
typedef unsigned int u32;

__device__ __forceinline__ u16 f2b(float f) {
  __hip_bfloat16 h = __float2bfloat16(f);
  return *reinterpret_cast<u16*>(&h);
}

#define MFMA16(a, b, c) __builtin_amdgcn_mfma_f32_16x16x32_bf16((a), (b), (c), 0, 0, 0)
#define MFMA32(a, b, c) __builtin_amdgcn_mfma_f32_32x32x16_bf16((a), (b), (c), 0, 0, 0)

// B=2 S=2048 D=1024 H=16 DC=64 HC=16 HD=64

// ---------- fp32 -> bf16 elementwise (n multiple of 1024) ----------
__global__ void k_cvt(const float* __restrict__ in, u16* __restrict__ out, int n) {
  int i = (blockIdx.x * 256 + threadIdx.x) * 4;
  if (i >= n) return;
  float4 v = *reinterpret_cast<const float4*>(in + i);
  ushort4 o;
  o.x = f2b(v.x); o.y = f2b(v.y); o.z = f2b(v.z); o.w = f2b(v.w);
  *reinterpret_cast<ushort4*>(out + i) = o;
}

// ---------- transpose + convert 1024x1024 fp32 weight -> bf16 W^T ----------
__global__ void k_wT(const float* __restrict__ W, u16* __restrict__ WT) {
  __shared__ float t[64][65];
  int tid = threadIdx.x;
  int r0 = (blockIdx.x & 15) << 6;   // k-tile
  int c0 = (blockIdx.x >> 4) << 6;   // n-tile
#pragma unroll
  for (int rep = 0; rep < 4; ++rep) {
    int e = tid + rep * 256;
    int r = e >> 4, c4 = (e & 15) << 2;
    float4 v = *reinterpret_cast<const float4*>(W + (size_t)(r0 + r) * 1024 + c0 + c4);
    t[r][c4] = v.x; t[r][c4 + 1] = v.y; t[r][c4 + 2] = v.z; t[r][c4 + 3] = v.w;
  }
  __syncthreads();
#pragma unroll
  for (int rep = 0; rep < 4; ++rep) {
    int e = tid + rep * 256;
    int c = e >> 4, r4 = (e & 15) << 2;
    ushort4 o;
    o.x = f2b(t[r4][c]); o.y = f2b(t[r4 + 1][c]);
    o.z = f2b(t[r4 + 2][c]); o.w = f2b(t[r4 + 3][c]);
    *reinterpret_cast<ushort4*>(WT + (size_t)(c0 + c) * 1024 + r0 + r4) = o;
  }
}

// ---------- z = coords @ Wc + bc ; Z bf16 [BH][S][16], zsq fp32 [BH][S] ----------
__global__ void k_z(const float* __restrict__ C, const float* __restrict__ Wc,
                    const float* __restrict__ bc, u16* __restrict__ Z,
                    float* __restrict__ zsq) {
  int gid = blockIdx.x * 256 + threadIdx.x;  // 65536 = (B*S)*H
  int bs = gid >> 4, h = gid & 15;
  const float* crow = C + (size_t)bs * 64;
  float acc[16];
#pragma unroll
  for (int c = 0; c < 16; ++c) acc[c] = bc[h * 16 + c];
  for (int k = 0; k < 64; ++k) {
    float cv = crow[k];
    const float* wr = Wc + (size_t)k * 256 + h * 16;
#pragma unroll
    for (int c = 0; c < 16; ++c) acc[c] = fmaf(cv, wr[c], acc[c]);
  }
  float sq = 0.f;
  u16 tmp[16];
#pragma unroll
  for (int c = 0; c < 16; ++c) { sq += acc[c] * acc[c]; tmp[c] = f2b(acc[c]); }
  int b = bs >> 11, s = bs & 2047;
  int bh = (b << 4) + h;
  u16* zr = Z + (((size_t)bh << 11) + s) * 16;
  *reinterpret_cast<uint4*>(zr) = *reinterpret_cast<uint4*>(tmp);
  *reinterpret_cast<uint4*>(zr + 8) = *reinterpret_cast<uint4*>(tmp + 8);
  zsq[((size_t)bh << 11) + s] = sq;
}

// ---------- GEMM C = A(bf16 MxK) * B(bf16, given as B^T NxK) + bias ----------
template <int OUTM>
__global__ __launch_bounds__(256) void k_gemm(const u16* __restrict__ A,
                                              const u16* __restrict__ BT,
                                              const float* __restrict__ bias,
                                              void* __restrict__ Cout,
                                              int M, int N, int K) {
  __shared__ u16 As[128][40];
  __shared__ u16 Bs[64][40];
  int nbn = N >> 6;
  int bm = blockIdx.x / nbn, bn = blockIdx.x % nbn;
  int tid = threadIdx.x, lane = tid & 63, w = tid >> 6;
  int wm = w >> 1, wn = w & 1;
  int l15 = lane & 15, lg = lane >> 4;
  f32x4 zero = {0.f, 0.f, 0.f, 0.f};
  f32x4 acc[4][2];
#pragma unroll
  for (int mi = 0; mi < 4; ++mi)
#pragma unroll
    for (int ni = 0; ni < 2; ++ni) acc[mi][ni] = zero;

  int ar = tid >> 2, aq = (tid & 3) << 3;
  const u16* Abase = A + (size_t)(bm * 128) * K;
  const u16* Bbase = BT + (size_t)(bn * 64) * K;

  for (int kk = 0; kk < K; kk += 32) {
    __syncthreads();
    *reinterpret_cast<uint4*>(&As[ar][aq]) =
        *reinterpret_cast<const uint4*>(Abase + (size_t)ar * K + kk + aq);
    *reinterpret_cast<uint4*>(&As[ar + 64][aq]) =
        *reinterpret_cast<const uint4*>(Abase + (size_t)(ar + 64) * K + kk + aq);
    *reinterpret_cast<uint4*>(&Bs[ar][aq]) =
        *reinterpret_cast<const uint4*>(Bbase + (size_t)ar * K + kk + aq);
    __syncthreads();
    bf16x8 af[4], bfr[2];
#pragma unroll
    for (int mi = 0; mi < 4; ++mi)
      af[mi] = *reinterpret_cast<const bf16x8*>(&As[wm * 64 + mi * 16 + l15][lg * 8]);
#pragma unroll
    for (int ni = 0; ni < 2; ++ni)
      bfr[ni] = *reinterpret_cast<const bf16x8*>(&Bs[wn * 32 + ni * 16 + l15][lg * 8]);
#pragma unroll
    for (int mi = 0; mi < 4; ++mi)
#pragma unroll
      for (int ni = 0; ni < 2; ++ni)
        acc[mi][ni] = MFMA16(af[mi], bfr[ni], acc[mi][ni]);
  }
#pragma unroll
  for (int mi = 0; mi < 4; ++mi) {
#pragma unroll
    for (int ni = 0; ni < 2; ++ni) {
      int col = bn * 64 + wn * 32 + ni * 16 + l15;
      float bb = bias[col];
#pragma unroll
      for (int j = 0; j < 4; ++j) {
        int row = bm * 128 + wm * 64 + mi * 16 + lg * 4 + j;
        float v = acc[mi][ni][j] + bb;
        if (OUTM == 0) {
          reinterpret_cast<float*>(Cout)[(size_t)row * N + col] = v;
        } else {
          int b = row >> 11, s = row & 2047, h = col >> 6, hd = col & 63;
          reinterpret_cast<u16*>(Cout)[((((size_t)(b * 16 + h) << 11) | s) << 6) + hd] = f2b(v);
        }
      }
    }
  }
}

// ---------- V [BH][S][64] -> VT [BH][64][S]  (bf16) ----------
__global__ void k_vT(const u16* __restrict__ V, u16* __restrict__ VT) {
  __shared__ u16 t[64][72];
  int tid = threadIdx.x;
  int bh = blockIdx.x >> 5;
  int s0 = (blockIdx.x & 31) << 6;
#pragma unroll
  for (int rep = 0; rep < 2; ++rep) {
    int e = tid + rep * 256;
    int sl = e >> 3, seg = (e & 7) << 3;
    *reinterpret_cast<uint4*>(&t[sl][seg]) =
        *reinterpret_cast<const uint4*>(V + ((size_t)(bh * 2048 + s0 + sl) << 6) + seg);
  }
  __syncthreads();
#pragma unroll
  for (int rep = 0; rep < 2; ++rep) {
    int e = tid + rep * 256;
    int hd = e >> 3, ss = (e & 7) << 3;
    u16 tmp[8];
#pragma unroll
    for (int i = 0; i < 8; ++i) tmp[i] = t[ss + i][hd];
    *reinterpret_cast<uint4*>(VT + ((size_t)(bh * 64 + hd) << 11) + s0 + ss) =
        *reinterpret_cast<uint4*>(tmp);
  }
}

// ---------- flash attention over gravity scores (32x32x16 MFMA, barrier-free loop) ----------
// Wave w = (th = w>>1, qh = w&1). QK: S^T quadrant [t-half th][q-half qh] via
// mfma(A=Zt strip, B=Zq): lane q = lane&31 (col), 16 t rows per lane.
// Same wave consumes its own P quadrant as the PV A-operand (k = its t-half,
// full d) -> P is per-wave LDS scratch, no barriers. oacc merged across
// t-halves once at the end. Z/VT MFMA fragments load directly from global.
__global__ __launch_bounds__(256, 4) void k_attn(const u16* __restrict__ Z,
                                                 const float* __restrict__ zsq,
                                                 const u16* __restrict__ VT,
                                                 const float* __restrict__ gamma,
                                                 u16* __restrict__ O) {
  // smem: [0,9216) P rows 144B x 64 (XOR-swizzled cols); [9216,17408) msq(2048 f32);
  // [17408,17920) psq[4][32]. End-phase oacc spill reuses [0,16384).
  __shared__ __align__(16) char smem[17920];
  float* msqf = reinterpret_cast<float*>(smem + 9216);
  float* psqf = reinterpret_cast<float*>(smem + 17408);

  int tid = threadIdx.x, lane = tid & 63, w = tid >> 6;
  int l31 = lane & 31, hi = lane >> 5;
  int hi4 = hi << 2, hi8 = hi << 3;
  int th = w >> 1, qh = w & 1, th32 = th << 5;
  int bh = blockIdx.x >> 5, qt = blockIdx.x & 31;
  int q0 = qt << 6;
  int h = bh & 15, bb = bh >> 4;
  float gm = gamma[h];
  float g = (gm > 15.f) ? gm : log1pf(__expf(gm));  // softplus
  float g2 = g * 1.4426950408889634f;               // fold log2(e) -> exp2
  float tg2 = 2.f * g2;

  const u16* Zb = Z + ((size_t)bh << 11) * 16;
  const float* zsb = zsq + ((size_t)bh << 11);
  const u16* VTb = VT + ((size_t)bh << 6) * 2048;

  // fill msq = -g2 * zsq (whole 2048 slice), once
  {
    int i8 = tid << 3;
    float4 v0 = *reinterpret_cast<const float4*>(zsb + i8);
    float4 v1 = *reinterpret_cast<const float4*>(zsb + i8 + 4);
    msqf[i8 + 0] = -g2 * v0.x; msqf[i8 + 1] = -g2 * v0.y;
    msqf[i8 + 2] = -g2 * v0.z; msqf[i8 + 3] = -g2 * v0.w;
    msqf[i8 + 4] = -g2 * v1.x; msqf[i8 + 5] = -g2 * v1.y;
    msqf[i8 + 6] = -g2 * v1.z; msqf[i8 + 7] = -g2 * v1.w;
  }
  __syncthreads();

  int q = (qh << 5) + l31;              // this lane's q (local to 64-tile)
  float gq = msqf[q0 + q];              // = -g2 * |z_q|^2
  char* Prow = smem + q * 144;
  u32 psw = ((u32)(q >> 3) & 3u) << 4;  // XOR swizzle, stays within 64B half

  // Q B-fragment: n = q, k = hi*8 + i  (K=16 exact)
  bf16x8 zq = *reinterpret_cast<const bf16x8*>(Zb + (size_t)(q0 + q) * 16 + hi8);
  // Zt A-fragment pointer: m = t, k = hi*8 + i
  const u16* zap = Zb + (size_t)(th32 + l31) * 16 + hi8;
  // VT B-fragment pointers: n = d = dh*32 + l31, k = t
  const u16* vbp0 = VTb + (size_t)l31 * 2048 + th32 + hi8;
  const u16* vbp1 = VTb + (size_t)(32 + l31) * 2048 + th32 + hi8;

  f32x16 oacc0 = {}, oacc1 = {};
  float psum = 0.f;

  bf16x8 zA_c = *reinterpret_cast<const bf16x8*>(zap);

  for (int tt = 0; tt < 32; ++tt) {
    const int t0 = tt << 6;
    // current-tile V fragments (consumed in PV, latency covered by QK+softmax)
    bf16x8 vb00 = *reinterpret_cast<const bf16x8*>(vbp0 + t0);
    bf16x8 vb01 = *reinterpret_cast<const bf16x8*>(vbp0 + t0 + 16);
    bf16x8 vb10 = *reinterpret_cast<const bf16x8*>(vbp1 + t0);
    bf16x8 vb11 = *reinterpret_cast<const bf16x8*>(vbp1 + t0 + 16);
    // next-tile Zt fragment
    bf16x8 zA_n = zA_c;
    if (tt < 31) zA_n = *reinterpret_cast<const bf16x8*>(zap + (size_t)(t0 + 64) * 16);

    f32x16 sc = MFMA32(zA_c, zq, (f32x16){});

    // softmax: p = exp2(min(tg2*dot + gq + mt, 0)); pack round-half-up to bf16
#pragma unroll
    for (int g4 = 0; g4 < 4; ++g4) {
      f32x4 mq = *reinterpret_cast<const f32x4*>(&msqf[t0 + th32 + (g4 << 3) + hi4]);
      float p0, p1, p2, p3;
      {
        float e0 = fminf(fmaf(tg2, sc[g4 * 4 + 0], gq + mq[0]), 0.f);
        float e1 = fminf(fmaf(tg2, sc[g4 * 4 + 1], gq + mq[1]), 0.f);
        float e2 = fminf(fmaf(tg2, sc[g4 * 4 + 2], gq + mq[2]), 0.f);
        float e3 = fminf(fmaf(tg2, sc[g4 * 4 + 3], gq + mq[3]), 0.f);
        p0 = exp2f(e0); p1 = exp2f(e1); p2 = exp2f(e2); p3 = exp2f(e3);
      }
      psum += (p0 + p1) + (p2 + p3);
      u32 b0 = __float_as_uint(p0) + 0x8000u;
      u32 b1 = __float_as_uint(p1) + 0x8000u;
      u32 b2 = __float_as_uint(p2) + 0x8000u;
      u32 b3 = __float_as_uint(p3) + 0x8000u;
      uint2 pk;
      pk.x = __builtin_amdgcn_perm(b1, b0, 0x07060302u);  // [hi16(b0), hi16(b1)]
      pk.y = __builtin_amdgcn_perm(b3, b2, 0x07060302u);
      int tcol = th32 + (g4 << 3) + hi4;
      *reinterpret_cast<uint2*>(Prow + (((u32)(tcol << 1)) ^ psw)) = pk;
    }

    // PV A-fragments from own P quadrant (same-wave LDS write->read, in-order)
    bf16x8 pa0 = *reinterpret_cast<const bf16x8*>(Prow + (((u32)((th32 + hi8) << 1)) ^ psw));
    bf16x8 pa1 = *reinterpret_cast<const bf16x8*>(Prow + (((u32)((th32 + 16 + hi8) << 1)) ^ psw));

    oacc0 = MFMA32(pa0, vb00, oacc0);
    oacc1 = MFMA32(pa0, vb10, oacc1);
    oacc0 = MFMA32(pa1, vb01, oacc0);
    oacc1 = MFMA32(pa1, vb11, oacc1);

    zA_c = zA_n;
  }

  // merge t-halves: waves 2,3 spill oacc+psum; waves 0,1 reduce and write O
  psum += __shfl_xor(psum, 32, 64);
  __syncthreads();
  if (w >= 2) {
    char* dst = smem + (w - 2) * 8192 + lane * 16;
#pragma unroll
    for (int c = 0; c < 4; ++c) {
      f32x4 v = {oacc0[c * 4 + 0], oacc0[c * 4 + 1], oacc0[c * 4 + 2], oacc0[c * 4 + 3]};
      *reinterpret_cast<f32x4*>(dst + c * 1024) = v;
    }
#pragma unroll
    for (int c = 0; c < 4; ++c) {
      f32x4 v = {oacc1[c * 4 + 0], oacc1[c * 4 + 1], oacc1[c * 4 + 2], oacc1[c * 4 + 3]};
      *reinterpret_cast<f32x4*>(dst + (c + 4) * 1024) = v;
    }
  }
  if (lane < 32) psqf[w * 32 + l31] = psum;
  __syncthreads();
  if (w < 2) {
    const char* src = smem + w * 8192 + lane * 16;
#pragma unroll
    for (int c = 0; c < 4; ++c) {
      f32x4 v = *reinterpret_cast<const f32x4*>(src + c * 1024);
      oacc0[c * 4 + 0] += v[0]; oacc0[c * 4 + 1] += v[1];
      oacc0[c * 4 + 2] += v[2]; oacc0[c * 4 + 3] += v[3];
    }
#pragma unroll
    for (int c = 0; c < 4; ++c) {
      f32x4 v = *reinterpret_cast<const f32x4*>(src + (c + 4) * 1024);
      oacc1[c * 4 + 0] += v[0]; oacc1[c * 4 + 1] += v[1];
      oacc1[c * 4 + 2] += v[2]; oacc1[c * 4 + 3] += v[3];
    }
#pragma unroll
    for (int g4 = 0; g4 < 4; ++g4) {
      f32x4 a = *reinterpret_cast<const f32x4*>(&psqf[qh * 32 + (g4 << 3) + hi4]);
      f32x4 b2 = *reinterpret_cast<const f32x4*>(&psqf[(qh + 2) * 32 + (g4 << 3) + hi4]);
#pragma unroll
      for (int j = 0; j < 4; ++j) {
        float inv = __builtin_amdgcn_rcpf(a[j] + b2[j]);
        int qrow = (g4 << 3) + hi4 + j;
        int srow = q0 + (qh << 5) + qrow;
        u16* orow = O + ((size_t)(bb * 2048 + srow) << 10) + h * 64 + l31;
        orow[0] = f2b(oacc0[g4 * 4 + j] * inv);
        orow[32] = f2b(oacc1[g4 * 4 + j] * inv);
      }
    }
  }
}

// ---------- updated_coords = coords @ Wn + bn (fp32) ----------
__global__ void k_coords(const float* __restrict__ C, const float* __restrict__ Wn,
                         const float* __restrict__ bn, float* __restrict__ out) {
  int gid = blockIdx.x * 256 + threadIdx.x;  // 262144
  int bs = gid >> 6, c = gid & 63;
  const float* crow = C + (size_t)bs * 64;
  float acc = bn[c];
#pragma unroll 8
  for (int k = 0; k < 64; ++k) acc = fmaf(crow[k], Wn[k * 64 + c], acc);
  out[gid] = acc;
}

extern "C" void kernel_launch(void* const* d_in, const int* in_sizes, int n_in,
                              void* d_out, int out_size, void* d_ws, size_t ws_size,
                              hipStream_t stream) {
  const float* hs     = (const float*)d_in[0];
  const float* coords = (const float*)d_in[1];
  const float* Wv     = (const float*)d_in[2];
  const float* bv     = (const float*)d_in[3];
  const float* Wc     = (const float*)d_in[4];
  const float* bc     = (const float*)d_in[5];
  const float* Wn     = (const float*)d_in[6];
  const float* bn     = (const float*)d_in[7];
  const float* Wo     = (const float*)d_in[8];
  const float* bo     = (const float*)d_in[9];
  const float* gamma  = (const float*)d_in[10];
  float* out_h = (float*)d_out;
  float* out_c = out_h + 4194304;

  char* ws = (char*)d_ws;
  u16*   HSb  = (u16*)(ws + 0);          // 8 MB   (reused as O after gemm1)
  u16*   O    = (u16*)(ws + 0);
  u16*   WvT  = (u16*)(ws + 8388608);    // 2 MB
  u16*   WoT  = (u16*)(ws + 10485760);   // 2 MB
  u16*   Zw   = (u16*)(ws + 12582912);   // 2 MB
  float* zsqw = (float*)(ws + 14680064); // 0.25 MB
  u16*   Vw   = (u16*)(ws + 14942208);   // 8 MB
  u16*   VTw  = (u16*)(ws + 23330816);   // 8 MB  -> total 31.7 MB

  k_cvt<<<4096, 256, 0, stream>>>(hs, HSb, 4194304);
  k_wT<<<256, 256, 0, stream>>>(Wv, WvT);
  k_wT<<<256, 256, 0, stream>>>(Wo, WoT);
  k_z<<<256, 256, 0, stream>>>(coords, Wc, bc, Zw, zsqw);
  k_gemm<1><<<512, 256, 0, stream>>>(HSb, WvT, bv, Vw, 4096, 1024, 1024);
  k_vT<<<1024, 256, 0, stream>>>(Vw, VTw);
  k_attn<<<1024, 256, 0, stream>>>(Zw, zsqw, VTw, gamma, O);
  k_gemm<0><<<512, 256, 0, stream>>>(O, WoT, bo, out_h, 4096, 1024, 1024);
  k_coords<<<1024, 256, 0, stream>>>(coords, Wn, bn, out_c);
}